// Round 3
// baseline (152.448 us; speedup 1.0000x reference)
//
#include <hip/hip_runtime.h>

// Neighbor search: 8192 queries x 16384 points, radius 0.08, unit cube.
// Output (flat INT32 — harness maps the reference's int64 to int32):
//   [n_pairs] neighbor point indices (row-major by query, ascending point
//   index within query), then [8193] row_splits.
//
// Bit-exactness: replicate numpy reference rounding:
//   q2 = (q0*q0 + q1*q1) + q2*q2   (each op rounded separately, no contraction)
//   dot = fma(q2,p2, fma(q1,p1, q0*p0))   (BLAS sgemm K-loop FMA chain)
//   d2  = (q2 + p2) - 2*dot               (2*dot exact; one rounding via fma)
//   R2  = (float)(0.08 * 0.08)            (double product, then narrowed)

#define N_POINTS 16384
#define N_QUERY  8192
#define QPW      4        // queries per wave
#define WPB      4        // waves per block (block = 256)
#define CHUNKS   (N_POINTS / 64)

__device__ __forceinline__ float sq3_np(float x, float y, float z) {
    // numpy: sum of [x*x, y*y, z*z] = (x*x + y*y) + z*z, each op rounded
    return __fadd_rn(__fadd_rn(__fmul_rn(x, x), __fmul_rn(y, y)), __fmul_rn(z, z));
}

__global__ __launch_bounds__(256) void count_kernel(const float* __restrict__ points,
                                                    const float* __restrict__ queries,
                                                    int* __restrict__ counts) {
    const int lane = threadIdx.x & 63;
    const int wave = threadIdx.x >> 6;
    const int qbase = (blockIdx.x * WPB + wave) * QPW;
    const float R2 = (float)(0.08 * 0.08);

    float qx[QPW], qy[QPW], qz[QPW], qq[QPW];
    int cnt[QPW];
#pragma unroll
    for (int i = 0; i < QPW; ++i) {
        const int q = qbase + i;
        qx[i] = queries[q * 3 + 0];
        qy[i] = queries[q * 3 + 1];
        qz[i] = queries[q * 3 + 2];
        qq[i] = sq3_np(qx[i], qy[i], qz[i]);
        cnt[i] = 0;
    }

    // software-pipelined point loads
    float px = points[lane * 3 + 0];
    float py = points[lane * 3 + 1];
    float pz = points[lane * 3 + 2];

    for (int c = 0; c < CHUNKS; ++c) {
        const float cpx = px, cpy = py, cpz = pz;
        if (c + 1 < CHUNKS) {
            const int p = (c + 1) * 64 + lane;
            px = points[p * 3 + 0];
            py = points[p * 3 + 1];
            pz = points[p * 3 + 2];
        }
        const float pp = sq3_np(cpx, cpy, cpz);
#pragma unroll
        for (int i = 0; i < QPW; ++i) {
            const float dot = __fmaf_rn(qz[i], cpz, __fmaf_rn(qy[i], cpy, __fmul_rn(qx[i], cpx)));
            const float s = __fadd_rn(qq[i], pp);
            const float d2 = __fmaf_rn(-2.0f, dot, s);
            cnt[i] += (d2 <= R2) ? 1 : 0;
        }
    }

#pragma unroll
    for (int i = 0; i < QPW; ++i) {
        int v = cnt[i];
#pragma unroll
        for (int off = 32; off > 0; off >>= 1) v += __shfl_down(v, off, 64);
        if (lane == 0) counts[qbase + i] = v;
    }
}

__global__ __launch_bounds__(1024) void scan_kernel(const int* __restrict__ counts,
                                                    int* __restrict__ splits,
                                                    int* __restrict__ out_splits) {
    __shared__ int tmp[1024];
    const int tid = threadIdx.x;
    int c[8];
    int s = 0;
#pragma unroll
    for (int j = 0; j < 8; ++j) {
        c[j] = counts[tid * 8 + j];
        s += c[j];
    }
    tmp[tid] = s;
    __syncthreads();
    for (int off = 1; off < 1024; off <<= 1) {
        int v = 0;
        if (tid >= off) v = tmp[tid - off];
        __syncthreads();
        tmp[tid] += v;
        __syncthreads();
    }
    int run = tmp[tid] - s;  // exclusive prefix of this thread's chunk
#pragma unroll
    for (int j = 0; j < 8; ++j) {
        splits[tid * 8 + j] = run;
        out_splits[tid * 8 + j] = run;
        run += c[j];
    }
    if (tid == 1023) {
        splits[N_QUERY] = run;
        out_splits[N_QUERY] = run;
    }
}

__global__ __launch_bounds__(256) void write_kernel(const float* __restrict__ points,
                                                    const float* __restrict__ queries,
                                                    const int* __restrict__ splits,
                                                    int* __restrict__ out_idx,
                                                    int n_pairs) {
    const int lane = threadIdx.x & 63;
    const int wave = threadIdx.x >> 6;
    const int qbase = (blockIdx.x * WPB + wave) * QPW;
    const float R2 = (float)(0.08 * 0.08);
    const unsigned long long below = (1ull << lane) - 1ull;

    float qx[QPW], qy[QPW], qz[QPW], qq[QPW];
    int base[QPW];
#pragma unroll
    for (int i = 0; i < QPW; ++i) {
        const int q = qbase + i;
        qx[i] = queries[q * 3 + 0];
        qy[i] = queries[q * 3 + 1];
        qz[i] = queries[q * 3 + 2];
        qq[i] = sq3_np(qx[i], qy[i], qz[i]);
        base[i] = splits[q];
    }

    float px = points[lane * 3 + 0];
    float py = points[lane * 3 + 1];
    float pz = points[lane * 3 + 2];

    for (int c = 0; c < CHUNKS; ++c) {
        const float cpx = px, cpy = py, cpz = pz;
        if (c + 1 < CHUNKS) {
            const int p = (c + 1) * 64 + lane;
            px = points[p * 3 + 0];
            py = points[p * 3 + 1];
            pz = points[p * 3 + 2];
        }
        const float pp = sq3_np(cpx, cpy, cpz);
        const int pidx = c * 64 + lane;
#pragma unroll
        for (int i = 0; i < QPW; ++i) {
            const float dot = __fmaf_rn(qz[i], cpz, __fmaf_rn(qy[i], cpy, __fmul_rn(qx[i], cpx)));
            const float s = __fadd_rn(qq[i], pp);
            const float d2 = __fmaf_rn(-2.0f, dot, s);
            const int pred = (d2 <= R2) ? 1 : 0;
            const unsigned long long m = __ballot(pred);
            if (pred) {
                const int off = __popcll(m & below);
                const int pos = base[i] + off;
                if (pos < n_pairs) out_idx[pos] = pidx;
            }
            base[i] += __popcll(m);
        }
    }
}

extern "C" void kernel_launch(void* const* d_in, const int* in_sizes, int n_in,
                              void* d_out, int out_size, void* d_ws, size_t ws_size,
                              hipStream_t stream) {
    const float* points = (const float*)d_in[0];   // [16384, 3]
    const float* queries = (const float*)d_in[1];  // [8192, 3]
    int* out = (int*)d_out;
    int* counts = (int*)d_ws;            // [8192]
    int* splits = counts + N_QUERY;      // [8193]
    const int n_pairs = out_size - (N_QUERY + 1);

    const int pass_blocks = N_QUERY / (WPB * QPW);  // 512
    count_kernel<<<pass_blocks, 256, 0, stream>>>(points, queries, counts);
    scan_kernel<<<1, 1024, 0, stream>>>(counts, splits, out + n_pairs);
    write_kernel<<<pass_blocks, 256, 0, stream>>>(points, queries, splits, out, n_pairs);
}